// Round 8
// baseline (338.200 us; speedup 1.0000x reference)
//
#include <hip/hip_runtime.h>
#include <hip/hip_bf16.h>
#include <cstddef>

#define B_   256
#define P_   196
#define DE_  2048
#define DD_  512
#define DA_  512
#define M_   (B_*P_)   // 50176

#define BM   32        // rows per block; grid 1568 = 8*196
#define KT   32        // K per macro-step
#define NKT  (DE_/KT)  // 64

typedef __attribute__((ext_vector_type(4)))  float f32x4;
typedef __attribute__((ext_vector_type(16))) float f32x16;
typedef __attribute__((ext_vector_type(8)))  short s16x8;

static __device__ __forceinline__ short f2bf(float x) {
    __hip_bfloat16 h = __float2bfloat16(x);
    return *reinterpret_cast<short*>(&h);
}

#define GLOAD_LDS16(g, l) __builtin_amdgcn_global_load_lds( \
    (const __attribute__((address_space(1))) void*)(g),     \
    (__attribute__((address_space(3))) void*)(l), 16, 0, 0)

// ---------------------------------------------------------------------------
// Kernel 0: pack W_enc [K][N] fp32 -> bf16 frags for mfma_f32_32x32x16_bf16.
// frag (kt2 in [0,128), nf in [0,16)): 64 lanes x 16B at unit (kt2*16+nf)*64+l;
// lane l, j in [0,8): W[kt2*16 + (l>>5)*8 + j][nf*32 + (l&31)]
// ---------------------------------------------------------------------------
__global__ __launch_bounds__(256) void pack_wenc(
        const float* __restrict__ W, __hip_bfloat16* __restrict__ out) {
    __shared__ float lds[16][DA_];          // 32 KB
    const int kt2 = blockIdx.x;             // 0..127
    const int t   = threadIdx.x;            // 0..255
#pragma unroll
    for (int i = 0; i < 32; ++i) {
        int e = i * 256 + t;                // 0..8191
        int k = e >> 9, n = e & 511;
        lds[k][n] = W[(size_t)(kt2 * 16 + k) * DA_ + n];
    }
    __syncthreads();
    short* o = reinterpret_cast<short*>(out);
#pragma unroll
    for (int i = 0; i < 4; ++i) {
        int u  = i * 256 + t;               // 0..1023
        int nf = u >> 6;                    // 0..15
        int l  = u & 63;
        int hi = l >> 5, c = l & 31;
        s16x8 w;
#pragma unroll
        for (int j = 0; j < 8; ++j)
            w[j] = f2bf(lds[hi * 8 + j][nf * 32 + c]);
        *reinterpret_cast<s16x8*>(o + (((size_t)kt2 * 16 + nf) * 64 + l) * 8) = w;
    }
}

// ---------------------------------------------------------------------------
// Kernel 1: att2p[b][a] = dh[b,:] @ W_dec[:,a] + b_dec[a] + b_enc[a]
// ---------------------------------------------------------------------------
__global__ __launch_bounds__(512) void att2_kernel(
        const float* __restrict__ dh, const float* __restrict__ W_dec,
        const float* __restrict__ b_dec, const float* __restrict__ b_enc,
        float* __restrict__ att2p) {
    __shared__ float s_dh[DD_];
    const int b = blockIdx.x;
    const int a = threadIdx.x;
    s_dh[a] = dh[(size_t)b * DD_ + a];
    __syncthreads();
    float acc = 0.f;
#pragma unroll 8
    for (int k = 0; k < DD_; ++k)
        acc += s_dh[k] * W_dec[(size_t)k * DA_ + a];
    att2p[(size_t)b * DA_ + a] = acc + b_dec[a] + b_enc[a];
}

// ---------------------------------------------------------------------------
// Kernel 2: GEMM 50176x512x2048 via mfma_f32_32x32x16_bf16 + fused epilogue.
// 256 thr = 4 waves; block tile 32 x 512 (full N); wave = 32 x 128 (4 n-frags,
// acc 64 regs). A: fp32 glds -> LDS quad-buffer (issued 3 macros ahead,
// in-row swizzled source). B: L2 -> VGPR, 2 frag-sets, 1-macro cover.
// 1 raw barrier/macro; 4 blocks/CU (16 waves/CU).
// ---------------------------------------------------------------------------
__global__ __launch_bounds__(256, 4) void gemm_att(
        const float* __restrict__ enc, const __hip_bfloat16* __restrict__ Bp,
        const float* __restrict__ att2p, const float* __restrict__ Wfull,
        float* __restrict__ att) {
    __shared__ float a_lds[4][BM * KT];     // 4 x 4 KB fp32
    __shared__ float red[BM][4];            // 512 B

    const int tid  = threadIdx.x;
    const int wave = tid >> 6;
    const int lane = tid & 63;
    const int hi   = lane >> 5;             // k-half of lane
    const int c31  = lane & 31;

    // XCD-aware swizzle (1568 = 8 * 196, bijective)
    const int p  = blockIdx.x;
    const int sw = (p & 7) * 196 + (p >> 3);
    const int block_row = sw * BM;

    // A glds staging: thread t stages 16 B of row (t>>3), in-row quad swizzled
    const int arow = tid >> 3;
    const int akq  = (tid & 7) ^ (arow & 7);
    const float* asrc = enc + (size_t)(block_row + arow) * DE_ + akq * 4;

    // A frag read: row = c31, two f32x4 at kq = h*4 + hi*2 + {0,1}, swizzled slot
    // slot(row,kq) = row*8 + (kq ^ (row&7)); float idx = slot*4
    const int ar_base = c31 * 8;
    const int ar_x    = c31 & 7;

    // B frag pointers (16 B units): frag (kt2, nf=wave*4+n) at (kt2*16+nf)*64+lane
    const s16x8* bbase = reinterpret_cast<const s16x8*>(Bp) + (size_t)(wave * 4) * 64 + lane;

    f32x16 acc[4] = {};
    s16x8 bfA[4], bfB[4];

#define LOAD_BF(dst, KT2) do {                                           \
        _Pragma("unroll")                                                \
        for (int n_ = 0; n_ < 4; ++n_)                                   \
            dst[n_] = bbase[((size_t)(KT2) * 16 + n_) * 64];             \
    } while (0)

#define GLDS_A(T) do {                                                   \
        const int tt_ = (T) > 63 ? 63 : (T);                             \
        GLOAD_LDS16(asrc + tt_ * KT, &a_lds[(T) & 3][tid * 4]);          \
    } while (0)

#define AF_READ(dst, buf, H) do {                                        \
        const int kq0_ = (H) * 4 + hi * 2;                               \
        f32x4 v0_ = *reinterpret_cast<const f32x4*>(                     \
            &(buf)[(ar_base + ((kq0_    ) ^ ar_x)) * 4]);                \
        f32x4 v1_ = *reinterpret_cast<const f32x4*>(                     \
            &(buf)[(ar_base + ((kq0_ + 1) ^ ar_x)) * 4]);                \
        s16x8 w_;                                                        \
        w_[0]=f2bf(v0_.x); w_[1]=f2bf(v0_.y); w_[2]=f2bf(v0_.z); w_[3]=f2bf(v0_.w); \
        w_[4]=f2bf(v1_.x); w_[5]=f2bf(v1_.y); w_[6]=f2bf(v1_.z); w_[7]=f2bf(v1_.w); \
        dst = w_;                                                        \
    } while (0)

#define MFMA4(afr, bfr) do {                                             \
        _Pragma("unroll")                                                \
        for (int n_ = 0; n_ < 4; ++n_)                                   \
            acc[n_] = __builtin_amdgcn_mfma_f32_32x32x16_bf16(           \
                          afr, bfr[n_], acc[n_], 0, 0, 0);               \
    } while (0)

    // ---- prologue: A(0..2) in flight, B(0) both halves loading ----
    GLDS_A(0); GLDS_A(1); GLDS_A(2);
    LOAD_BF(bfA, 0);                 // kt2 = 0 (h0 of macro 0)
    LOAD_BF(bfB, 1);                 // kt2 = 1 (h1 of macro 0)
    asm volatile("s_waitcnt vmcnt(10)" ::: "memory");   // A(0) done
    __builtin_amdgcn_s_barrier();
    __builtin_amdgcn_sched_barrier(0);

#pragma clang loop unroll(disable)
    for (int t = 0; t < NKT; ++t) {
        const float* abuf = a_lds[t & 3];
        const int tn = (t + 1 < NKT) ? t + 1 : NKT - 1;   // clamped next macro
        s16x8 af0, af1;
        // h0
        AF_READ(af0, abuf, 0);
        MFMA4(af0, bfA);                       // auto-waits bfA (retires A(t+1))
        LOAD_BF(bfA, 2 * tn);                  // B(t+1, h0)
        // h1
        AF_READ(af1, abuf, 1);
        MFMA4(af1, bfB);
        LOAD_BF(bfB, 2 * tn + 1);              // B(t+1, h1)
        __builtin_amdgcn_sched_barrier(0);
        GLDS_A(t + 3);                         // clamped re-issue keeps FIFO uniform
        __builtin_amdgcn_sched_barrier(0);
        asm volatile("s_waitcnt vmcnt(10) lgkmcnt(0)" ::: "memory");
        __builtin_amdgcn_s_barrier();
        __builtin_amdgcn_sched_barrier(0);
    }

    // ---- fused epilogue: att[R] = sum_n relu(att1 + att2) * Wfull ----
    const int b0    = block_row / P_;
    const int b1    = min(b0 + 1, B_ - 1);
    const int split = (b0 + 1) * P_;
    float wf[4], a20[4], a21[4];
#pragma unroll
    for (int n = 0; n < 4; ++n) {
        const int col = (wave * 4 + n) * 32 + c31;
        wf[n]  = Wfull[col];
        a20[n] = att2p[(size_t)b0 * DA_ + col];
        a21[n] = att2p[(size_t)b1 * DA_ + col];
    }
#pragma unroll
    for (int r = 0; r < 16; ++r) {
        const int row_local = (r & 3) + 8 * (r >> 2) + 4 * hi;
        const int R = block_row + row_local;
        const bool hiB = (R >= split);
        float s = 0.f;
#pragma unroll
        for (int n = 0; n < 4; ++n) {
            float a2 = hiB ? a21[n] : a20[n];
            float v  = acc[n][r] + a2;
            v = fmaxf(v, 0.f);
            s += v * wf[n];
        }
#pragma unroll
        for (int off = 1; off < 32; off <<= 1)
            s += __shfl_xor(s, off, 64);
        if (c31 == 0) red[row_local][wave] = s;
    }
    __syncthreads();
    if (tid < BM) {
        att[block_row + tid] = red[tid][0] + red[tid][1] + red[tid][2] + red[tid][3];
    }
#undef LOAD_BF
#undef GLDS_A
#undef AF_READ
#undef MFMA4
}

// ---------------------------------------------------------------------------
// Kernel 3: softmax over P per batch -> alpha (bfull dropped: shift-invariant)
// ---------------------------------------------------------------------------
__global__ __launch_bounds__(256) void softmax_kernel(
        const float* __restrict__ att, float* __restrict__ alpha) {
    const int b = blockIdx.x;
    const int t = threadIdx.x;
    __shared__ float sred[4];
    float v = (t < P_) ? att[(size_t)b * P_ + t] : -1e30f;
    float m = v;
#pragma unroll
    for (int off = 1; off < 64; off <<= 1) m = fmaxf(m, __shfl_xor(m, off, 64));
    if ((t & 63) == 0) sred[t >> 6] = m;
    __syncthreads();
    const float mall = fmaxf(fmaxf(sred[0], sred[1]), fmaxf(sred[2], sred[3]));
    __syncthreads();
    float e = (t < P_) ? expf(v - mall) : 0.f;
    float s = e;
#pragma unroll
    for (int off = 1; off < 64; off <<= 1) s += __shfl_xor(s, off, 64);
    if ((t & 63) == 0) sred[t >> 6] = s;
    __syncthreads();
    const float stot = sred[0] + sred[1] + sred[2] + sred[3];
    if (t < P_) alpha[(size_t)b * P_ + t] = e / stot;
}

// ---------------------------------------------------------------------------
// Kernel 4: context[b][e] = sum_p alpha[b][p] * enc[b][p][e]
// ---------------------------------------------------------------------------
__global__ __launch_bounds__(256) void context_kernel(
        const float* __restrict__ enc, const float* __restrict__ alpha,
        float* __restrict__ ctx) {
    const int b = blockIdx.x;
    const int e = blockIdx.y * 1024 + threadIdx.x * 4;
    __shared__ float s_alpha[P_];
    if (threadIdx.x < P_) s_alpha[threadIdx.x] = alpha[(size_t)b * P_ + threadIdx.x];
    __syncthreads();
    f32x4 acc = {0.f, 0.f, 0.f, 0.f};
    const float* base = enc + (size_t)b * P_ * DE_ + e;
#pragma unroll 4
    for (int p = 0; p < P_; ++p) {
        f32x4 v = *reinterpret_cast<const f32x4*>(base + (size_t)p * DE_);
        acc += s_alpha[p] * v;
    }
    *reinterpret_cast<f32x4*>(ctx + (size_t)b * DE_ + e) = acc;
}

// ---------------------------------------------------------------------------
extern "C" void kernel_launch(void* const* d_in, const int* in_sizes, int n_in,
                              void* d_out, int out_size, void* d_ws, size_t ws_size,
                              hipStream_t stream) {
    const float* enc    = (const float*)d_in[0];
    const float* dh     = (const float*)d_in[1];
    const float* W_enc  = (const float*)d_in[2];
    const float* b_enc  = (const float*)d_in[3];
    const float* W_dec  = (const float*)d_in[4];
    const float* b_dec  = (const float*)d_in[5];
    const float* W_full = (const float*)d_in[6];

    float* out       = (float*)d_out;
    float* ctx_out   = out;                       // [B,DE]
    float* alpha_out = out + (size_t)B_ * DE_;    // [B,P]

    char* ws = (char*)d_ws;
    __hip_bfloat16* Bp = (__hip_bfloat16*)ws;                        // 2 MB
    float* att2p = (float*)(ws + 2u * 1024 * 1024);                  // 512 KB
    float* att   = (float*)(ws + 2u * 1024 * 1024 + 512u * 1024);    // 200 KB

    pack_wenc     <<<128,           256, 0, stream>>>(W_enc, Bp);
    att2_kernel   <<<B_,            512, 0, stream>>>(dh, W_dec, b_dec, b_enc, att2p);
    gemm_att      <<<M_ / BM,       256, 0, stream>>>(enc, Bp, att2p, W_full, att);
    softmax_kernel<<<B_,            256, 0, stream>>>(att, alpha_out);
    context_kernel<<<dim3(B_, 2),   256, 0, stream>>>(enc, alpha_out, ctx_out);
}

// Round 9
// 280.946 us; speedup vs baseline: 1.2038x; 1.2038x over previous
//
#include <hip/hip_runtime.h>
#include <hip/hip_bf16.h>
#include <cstddef>

#define B_   256
#define P_   196
#define DE_  2048
#define DD_  512
#define DA_  512
#define M_   (B_*P_)   // 50176

#define BM   128
#define KT   32
#define NKT  (DE_/KT)  // 64

typedef __attribute__((ext_vector_type(4))) float f32x4;
typedef __attribute__((ext_vector_type(8))) short s16x8;

static __device__ __forceinline__ short f2bf(float x) {
    __hip_bfloat16 h = __float2bfloat16(x);
    return *reinterpret_cast<short*>(&h);
}

#define GLOAD_LDS16(g, l) __builtin_amdgcn_global_load_lds( \
    (const __attribute__((address_space(1))) void*)(g),     \
    (__attribute__((address_space(3))) void*)(l), 16, 0, 0)

// ---------------------------------------------------------------------------
// Kernel 0: pack W_enc [K][N] fp32 -> bf16 fragment-ready + XOR-swizzled:
//   elem (kt, n, sp*8+j) holds W[kt*32 + s*8 + j][n], s = sp ^ ((n>>1)&3)
// ---------------------------------------------------------------------------
__global__ void pack_wenc(const float* __restrict__ W, __hip_bfloat16* __restrict__ out) {
    __shared__ float lds[KT][128 + 1];
    const int kt = blockIdx.x;
    const int n0 = blockIdx.y * 128;
    const int t  = threadIdx.x;
#pragma unroll
    for (int i = 0; i < 16; ++i) {
        int e  = t + i * 256;
        int kl = e >> 7;
        int nl = e & 127;
        lds[kl][nl] = W[(size_t)(kt * KT + kl) * DA_ + n0 + nl];
    }
    __syncthreads();
    short* o16 = reinterpret_cast<short*>(out);
#pragma unroll
    for (int i = 0; i < 2; ++i) {
        int task = t + i * 256;
        int nl   = task >> 2;
        int s    = task & 3;
        int n    = n0 + nl;
        int sp   = s ^ ((n >> 1) & 3);
        s16x8 w;
#pragma unroll
        for (int j = 0; j < 8; ++j)
            w[j] = f2bf(lds[s * 8 + j][nl]);
        *reinterpret_cast<s16x8*>(o16 + (size_t)kt * (DA_ * KT) + n * KT + sp * 8) = w;
    }
}

// ---------------------------------------------------------------------------
// Kernel 1: att2p[b][a] = dh[b,:] @ W_dec[:,a] + b_dec[a] + b_enc[a]
// ---------------------------------------------------------------------------
__global__ __launch_bounds__(512) void att2_kernel(
        const float* __restrict__ dh, const float* __restrict__ W_dec,
        const float* __restrict__ b_dec, const float* __restrict__ b_enc,
        float* __restrict__ att2p) {
    __shared__ float s_dh[DD_];
    const int b = blockIdx.x;
    const int a = threadIdx.x;
    s_dh[a] = dh[(size_t)b * DD_ + a];
    __syncthreads();
    float acc = 0.f;
#pragma unroll 8
    for (int k = 0; k < DD_; ++k)
        acc += s_dh[k] * W_dec[(size_t)k * DA_ + a];
    att2p[(size_t)b * DA_ + a] = acc + b_dec[a] + b_enc[a];
}

// ---------------------------------------------------------------------------
// Kernel 2: faithful m97-structure GEMM. 128x128 tile, 4 waves (64x64 each),
// BK=32, single-buffered LDS, two __syncthreads per K-step, A fp32 + B bf16
// both staged via global_load_lds, fragment reads swizzled, cvt-on-read for A.
// NO inline asm / sched_barrier / counted vmcnt — compiler schedules.
// Grid 1568 = 392 M-tiles x 4 N-panels; panels of one M-tile share an XCD.
// ---------------------------------------------------------------------------
__global__ __launch_bounds__(256, 2) void gemm_att(
        const float* __restrict__ enc, const __hip_bfloat16* __restrict__ Bp,
        const float* __restrict__ att2p, const float* __restrict__ Wfull,
        float* __restrict__ att_part) {
    __shared__ float a_lds[BM * KT];              // 16 KB fp32
    __shared__ __hip_bfloat16 b_lds[128 * KT];    // 8 KB bf16
    __shared__ float red[BM][2];                  // 1 KB

    const int tid  = threadIdx.x;
    const int wave = tid >> 6;
    const int lane = tid & 63;
    const int g    = lane >> 4;        // k-group
    const int c    = lane & 15;
    const int wm   = wave >> 1;        // wave row-half
    const int wn   = wave & 1;         // wave col-half

    // bid -> (mtile, panel), panels of one mtile 8 apart (same XCD rr slot)
    const int p     = blockIdx.x;
    const int q     = p >> 5;
    const int t5    = p & 31;
    const int panel = t5 >> 3;
    const int mtile = q * 8 + (t5 & 7);
    const int block_row = mtile * BM;

    // ---- A staging (4 glds16/thread): unit u = i*256+tid -> row u>>3, slot u&7
    // LDS unit (r,s) holds source slot s ^ (r&7); (r&7) == (tid>>3)&7 for all i
    const int a_sslot = (tid & 7) ^ ((tid >> 3) & 7);
    const float* a_src0 = enc + (size_t)(block_row + (tid >> 3)) * DE_ + a_sslot * 4;

    // ---- B staging (2 glds16/thread): linear 8 KB chunk of the pack
    const char* b_src0 = (const char*)Bp + (size_t)panel * 8192 + (size_t)tid * 16;

    // ---- A frag read offsets: row rr = wm*64+mt*16+c; (rr&7)==c&7
    const int ax = c & 7;
    const int ao0 = (((2 * g)     ^ ax)) * 4;     // float offset of k g*8..+3
    const int ao1 = (((2 * g + 1) ^ ax)) * 4;     // float offset of k g*8+4..+7
    // ---- B frag read: col nl = wn*64+nt*16+c; slot = g ^ ((c>>1)&3)
    const int bslot8 = (g ^ ((c >> 1) & 3)) * 8;

    f32x4 acc[4][4] = {};

    for (int kt = 0; kt < NKT; ++kt) {
        __syncthreads();               // previous iteration's readers done
        // stage A (fp32) + B (bf16)
#pragma unroll
        for (int i = 0; i < 4; ++i)
            GLOAD_LDS16(a_src0 + (size_t)i * 32 * DE_ + kt * KT,
                        &a_lds[(i * 256 + tid) * 4]);
#pragma unroll
        for (int i = 0; i < 2; ++i)
            GLOAD_LDS16(b_src0 + (size_t)kt * 32768 + i * 4096,
                        &b_lds[(i * 256 + tid) * 8]);
        __syncthreads();               // vmcnt(0) drain: tile ready
        // fragments
        s16x8 af[4], bf[4];
#pragma unroll
        for (int mt = 0; mt < 4; ++mt) {
            const float* base = a_lds + (wm * 64 + mt * 16 + c) * KT;
            f32x4 v0 = *reinterpret_cast<const f32x4*>(base + ao0);
            f32x4 v1 = *reinterpret_cast<const f32x4*>(base + ao1);
            s16x8 w;
            w[0] = f2bf(v0.x); w[1] = f2bf(v0.y); w[2] = f2bf(v0.z); w[3] = f2bf(v0.w);
            w[4] = f2bf(v1.x); w[5] = f2bf(v1.y); w[6] = f2bf(v1.z); w[7] = f2bf(v1.w);
            af[mt] = w;
        }
#pragma unroll
        for (int nt = 0; nt < 4; ++nt)
            bf[nt] = *reinterpret_cast<const s16x8*>(
                         b_lds + (wn * 64 + nt * 16 + c) * KT + bslot8);
#pragma unroll
        for (int mt = 0; mt < 4; ++mt)
#pragma unroll
            for (int nt = 0; nt < 4; ++nt)
                acc[mt][nt] = __builtin_amdgcn_mfma_f32_16x16x32_bf16(
                                  af[mt], bf[nt], acc[mt][nt], 0, 0, 0);
    }

    // ---- fused epilogue: partial relu-dot over this block's 128 cols ----
    const int b0    = block_row / P_;
    const int b1    = min(b0 + 1, B_ - 1);
    const int split = (b0 + 1) * P_;
    float wf[4], a20[4], a21[4];
#pragma unroll
    for (int nt = 0; nt < 4; ++nt) {
        const int col = panel * 128 + wn * 64 + nt * 16 + c;
        wf[nt]  = Wfull[col];
        a20[nt] = att2p[(size_t)b0 * DA_ + col];
        a21[nt] = att2p[(size_t)b1 * DA_ + col];
    }
#pragma unroll
    for (int mt = 0; mt < 4; ++mt) {
#pragma unroll
        for (int qq = 0; qq < 4; ++qq) {
            const int row_local = wm * 64 + mt * 16 + g * 4 + qq;
            const int R = block_row + row_local;
            const bool hiB = (R >= split);
            float s = 0.f;
#pragma unroll
            for (int nt = 0; nt < 4; ++nt) {
                float a2 = hiB ? a21[nt] : a20[nt];
                float v  = acc[mt][nt][qq] + a2;
                v = fmaxf(v, 0.f);
                s += v * wf[nt];
            }
#pragma unroll
            for (int off = 1; off < 16; off <<= 1)
                s += __shfl_xor(s, off, 64);
            if (c == 0) red[row_local][wn] = s;
        }
    }
    __syncthreads();
    if (tid < BM)
        att_part[(size_t)panel * M_ + block_row + tid] = red[tid][0] + red[tid][1];
}

// ---------------------------------------------------------------------------
// Kernel 3: softmax over P per batch -> alpha (sums the 4 panel partials)
// ---------------------------------------------------------------------------
__global__ __launch_bounds__(256) void softmax_kernel(
        const float* __restrict__ att_part, float* __restrict__ alpha) {
    const int b = blockIdx.x;
    const int t = threadIdx.x;
    __shared__ float sred[4];
    float v = -1e30f;
    if (t < P_) {
        const size_t R = (size_t)b * P_ + t;
        v = att_part[R] + att_part[M_ + R] + att_part[2 * M_ + R] + att_part[3 * M_ + R];
    }
    float m = v;
#pragma unroll
    for (int off = 1; off < 64; off <<= 1) m = fmaxf(m, __shfl_xor(m, off, 64));
    if ((t & 63) == 0) sred[t >> 6] = m;
    __syncthreads();
    const float mall = fmaxf(fmaxf(sred[0], sred[1]), fmaxf(sred[2], sred[3]));
    __syncthreads();
    float e = (t < P_) ? expf(v - mall) : 0.f;
    float s = e;
#pragma unroll
    for (int off = 1; off < 64; off <<= 1) s += __shfl_xor(s, off, 64);
    if ((t & 63) == 0) sred[t >> 6] = s;
    __syncthreads();
    const float stot = sred[0] + sred[1] + sred[2] + sred[3];
    if (t < P_) alpha[(size_t)b * P_ + t] = e / stot;
}

// ---------------------------------------------------------------------------
// Kernel 4: context[b][e] = sum_p alpha[b][p] * enc[b][p][e]
// ---------------------------------------------------------------------------
__global__ __launch_bounds__(256) void context_kernel(
        const float* __restrict__ enc, const float* __restrict__ alpha,
        float* __restrict__ ctx) {
    const int b = blockIdx.x;
    const int e = blockIdx.y * 1024 + threadIdx.x * 4;
    __shared__ float s_alpha[P_];
    if (threadIdx.x < P_) s_alpha[threadIdx.x] = alpha[(size_t)b * P_ + threadIdx.x];
    __syncthreads();
    f32x4 acc = {0.f, 0.f, 0.f, 0.f};
    const float* base = enc + (size_t)b * P_ * DE_ + e;
#pragma unroll 4
    for (int p = 0; p < P_; ++p) {
        f32x4 v = *reinterpret_cast<const f32x4*>(base + (size_t)p * DE_);
        acc += s_alpha[p] * v;
    }
    *reinterpret_cast<f32x4*>(ctx + (size_t)b * DE_ + e) = acc;
}

// ---------------------------------------------------------------------------
extern "C" void kernel_launch(void* const* d_in, const int* in_sizes, int n_in,
                              void* d_out, int out_size, void* d_ws, size_t ws_size,
                              hipStream_t stream) {
    const float* enc    = (const float*)d_in[0];
    const float* dh     = (const float*)d_in[1];
    const float* W_enc  = (const float*)d_in[2];
    const float* b_enc  = (const float*)d_in[3];
    const float* W_dec  = (const float*)d_in[4];
    const float* b_dec  = (const float*)d_in[5];
    const float* W_full = (const float*)d_in[6];

    float* out       = (float*)d_out;
    float* ctx_out   = out;                       // [B,DE]
    float* alpha_out = out + (size_t)B_ * DE_;    // [B,P]

    char* ws = (char*)d_ws;
    __hip_bfloat16* Bp  = (__hip_bfloat16*)ws;                        // 2 MB
    float* att2p    = (float*)(ws + 2u * 1024 * 1024);                // 512 KB
    float* att_part = (float*)(ws + 2u * 1024 * 1024 + 512u * 1024); // 4 x 200 KB

    pack_wenc     <<<dim3(NKT, 4),   256, 0, stream>>>(W_enc, Bp);
    att2_kernel   <<<B_,             512, 0, stream>>>(dh, W_dec, b_dec, b_enc, att2p);
    gemm_att      <<<(M_ / BM) * 4,  256, 0, stream>>>(enc, Bp, att2p, W_full, att_part);
    softmax_kernel<<<B_,             256, 0, stream>>>(att_part, alpha_out);
    context_kernel<<<dim3(B_, 2),    256, 0, stream>>>(enc, alpha_out, ctx_out);
}